// Round 3
// baseline (143.970 us; speedup 1.0000x reference)
//
#include <hip/hip_runtime.h>
#include <math.h>

#define H      128
#define FCN    400
#define L1N    500
#define L2N    63
#define STEPS  65536
#define NBLK   100
#define NWAVE  (NBLK * 4)

__device__ __forceinline__ float sigmoidf_(float v) {
    return 1.0f / (1.0f + expf(-v));
}

__device__ __forceinline__ float wave_reduce(float v) {
#pragma unroll
    for (int off = 32; off > 0; off >>= 1)
        v += __shfl_down(v, off, 64);
    return v;
}

// Agent(device)-scope coherent accesses: safe across non-coherent per-XCD L2s.
__device__ __forceinline__ float cohLoad(const float* p) {
    return __hip_atomic_load(p, __ATOMIC_RELAXED, __HIP_MEMORY_SCOPE_AGENT);
}
__device__ __forceinline__ void cohStore(float* p, float v) {
    __hip_atomic_store(p, v, __ATOMIC_RELAXED, __HIP_MEMORY_SCOPE_AGENT);
}

// Grid-wide barrier: generation counter + arrival count in global memory.
// Requires all NBLK blocks co-resident (100 blocks of 256 thr on 256 CUs: yes).
__device__ __forceinline__ void grid_barrier(int* cnt, int* gen) {
    __syncthreads();
    if (threadIdx.x == 0) {
        int g = __hip_atomic_load(gen, __ATOMIC_RELAXED, __HIP_MEMORY_SCOPE_AGENT);
        int a = __hip_atomic_fetch_add(cnt, 1, __ATOMIC_ACQ_REL, __HIP_MEMORY_SCOPE_AGENT);
        if (a == NBLK - 1) {
            __hip_atomic_store(cnt, 0, __ATOMIC_RELAXED, __HIP_MEMORY_SCOPE_AGENT);
            __hip_atomic_fetch_add(gen, 1, __ATOMIC_RELEASE, __HIP_MEMORY_SCOPE_AGENT);
        } else {
            while (__hip_atomic_load(gen, __ATOMIC_ACQUIRE, __HIP_MEMORY_SCOPE_AGENT) == g) {
                __builtin_amdgcn_s_sleep(1);
            }
        }
    }
    __syncthreads();
}

__global__ __launch_bounds__(256) void fused_kernel(
    const float* __restrict__ x_last,  // [H] last input row
    const float* __restrict__ W_ih,    // [3, 4H, H]
    const float* __restrict__ b_ih,    // [3, 4H]
    const float* __restrict__ b_hh,    // [3, 4H]
    const float* __restrict__ W_fc,    // [FCN, H]
    const float* __restrict__ b_fc,
    const float* __restrict__ W_l1,    // [L1N, FCN]
    const float* __restrict__ b_l1,
    const float* __restrict__ W_l2,    // [L2N, L1N]
    const float* __restrict__ b_l2,
    float* __restrict__ hb,            // ws: [3*H]
    float* __restrict__ fc_o,          // ws: [FCN]
    float* __restrict__ l1_o,          // ws: [L1N]
    int* __restrict__ bar,             // ws: {cnt, gen} (zeroed via memsetAsync)
    float* __restrict__ out)           // [L2N]
{
    __shared__ __align__(16) float s_x[512];
    const int tid  = threadIdx.x;
    const int lane = tid & 63;
    const int gw   = (blockIdx.x << 2) | (tid >> 6);  // global wave id, 0..399
    int* cnt = bar;
    int* gen = bar + 1;

    // ---- 3 LSTM cell layers (h0=c0=0: only i,g,o gates; W_hh contributes 0)
    for (int l = 0; l < 3; ++l) {
        if (tid < H)
            s_x[tid] = (l == 0) ? x_last[tid] : cohLoad(&hb[(l - 1) * H + tid]);
        __syncthreads();
        if (gw < H) {
            const float* Wl = W_ih + (size_t)l * 4 * H * H;
            const float2 xv = ((const float2*)s_x)[lane];
            const float2 a = ((const float2*)(Wl + (size_t)(0 * H + gw) * H))[lane];
            const float2 b = ((const float2*)(Wl + (size_t)(2 * H + gw) * H))[lane];
            const float2 c = ((const float2*)(Wl + (size_t)(3 * H + gw) * H))[lane];
            float pi = fmaf(a.x, xv.x, a.y * xv.y);
            float pg = fmaf(b.x, xv.x, b.y * xv.y);
            float po = fmaf(c.x, xv.x, c.y * xv.y);
            pi = wave_reduce(pi);
            pg = wave_reduce(pg);
            po = wave_reduce(po);
            if (lane == 0) {
                const float* bi = b_ih + l * 4 * H;
                const float* bh = b_hh + l * 4 * H;
                const float ig = pi + bi[0 * H + gw] + bh[0 * H + gw];
                const float gg = pg + bi[2 * H + gw] + bh[2 * H + gw];
                const float og = po + bi[3 * H + gw] + bh[3 * H + gw];
                const float cc = sigmoidf_(ig) * tanhf(gg);
                cohStore(&hb[l * H + gw], sigmoidf_(og) * tanhf(cc));
            }
        }
        grid_barrier(cnt, gen);
    }

    // ---- FC: [FCN,128] @ h2
    if (tid < H) s_x[tid] = cohLoad(&hb[2 * H + tid]);
    __syncthreads();
    if (gw < FCN) {
        const float2 xv = ((const float2*)s_x)[lane];
        const float2 wv = ((const float2*)(W_fc + (size_t)gw * H))[lane];
        float p = wave_reduce(fmaf(wv.x, xv.x, wv.y * xv.y));
        if (lane == 0) cohStore(&fc_o[gw], p + b_fc[gw]);
    }
    grid_barrier(cnt, gen);

    // ---- L1: [L1N,FCN] @ fc_o
    for (int i = tid; i < FCN; i += 256) s_x[i] = cohLoad(&fc_o[i]);
    __syncthreads();
    for (int row = gw; row < L1N; row += NWAVE) {
        const float4* w4 = (const float4*)(W_l1 + (size_t)row * FCN);
        const float4* x4 = (const float4*)s_x;
        float acc = 0.f;
        for (int k = lane; k < (FCN >> 2); k += 64) {
            const float4 a = w4[k];
            const float4 v = x4[k];
            acc = fmaf(a.x, v.x, acc);
            acc = fmaf(a.y, v.y, acc);
            acc = fmaf(a.z, v.z, acc);
            acc = fmaf(a.w, v.w, acc);
        }
        acc = wave_reduce(acc);
        if (lane == 0) cohStore(&l1_o[row], acc + b_l1[row]);
    }
    grid_barrier(cnt, gen);

    // ---- L2: [L2N,L1N] @ l1_o -> out
    for (int i = tid; i < L1N; i += 256) s_x[i] = cohLoad(&l1_o[i]);
    __syncthreads();
    if (gw < L2N) {
        const float4* w4 = (const float4*)(W_l2 + (size_t)gw * L1N);
        const float4* x4 = (const float4*)s_x;
        float acc = 0.f;
        for (int k = lane; k < (L1N >> 2); k += 64) {
            const float4 a = w4[k];
            const float4 v = x4[k];
            acc = fmaf(a.x, v.x, acc);
            acc = fmaf(a.y, v.y, acc);
            acc = fmaf(a.z, v.z, acc);
            acc = fmaf(a.w, v.w, acc);
        }
        acc = wave_reduce(acc);
        if (lane == 0) out[gw] = acc + b_l2[gw];
    }
}

extern "C" void kernel_launch(void* const* d_in, const int* in_sizes, int n_in,
                              void* d_out, int out_size, void* d_ws, size_t ws_size,
                              hipStream_t stream) {
    const float* inputs = (const float*)d_in[0];
    const float* W_ih   = (const float*)d_in[1];
    // d_in[2] = W_hh (unused: h0 = 0)
    const float* b_ih   = (const float*)d_in[3];
    const float* b_hh   = (const float*)d_in[4];
    const float* W_fc   = (const float*)d_in[5];
    const float* b_fc   = (const float*)d_in[6];
    const float* W_l1   = (const float*)d_in[7];
    const float* b_l1   = (const float*)d_in[8];
    const float* W_l2   = (const float*)d_in[9];
    const float* b_l2   = (const float*)d_in[10];
    float* out = (float*)d_out;

    float* ws   = (float*)d_ws;
    float* hb   = ws + 0;     // 3*128
    float* fc_o = ws + 512;   // 400
    float* l1_o = ws + 1024;  // 500
    int*   bar  = (int*)((char*)d_ws + 16384);

    const float* x_last = inputs + (size_t)(STEPS - 1) * H;

    hipMemsetAsync(bar, 0, 64, stream);
    fused_kernel<<<NBLK, 256, 0, stream>>>(
        x_last, W_ih, b_ih, b_hh, W_fc, b_fc, W_l1, b_l1, W_l2, b_l2,
        hb, fc_o, l1_o, bar, out);
}

// Round 4
// 119.413 us; speedup vs baseline: 1.2057x; 1.2057x over previous
//
#include <hip/hip_runtime.h>
#include <math.h>

#define H      128
#define FCN    400
#define L1N    500
#define L2N    63
#define STEPS  65536
#define NBLK   100
#define NWAVE  (NBLK * 4)   // 400 waves

__device__ __forceinline__ float sigmoidf_(float v) {
    return 1.0f / (1.0f + expf(-v));
}

__device__ __forceinline__ float wave_reduce(float v) {
#pragma unroll
    for (int off = 32; off > 0; off >>= 1)
        v += __shfl_down(v, off, 64);
    return v;
}

// Agent(device)-scope coherent accesses: safe across non-coherent per-XCD L2s.
__device__ __forceinline__ float cohLoad(const float* p) {
    return __hip_atomic_load(p, __ATOMIC_RELAXED, __HIP_MEMORY_SCOPE_AGENT);
}
__device__ __forceinline__ void cohStore(float* p, float v) {
    __hip_atomic_store(p, v, __ATOMIC_RELAXED, __HIP_MEMORY_SCOPE_AGENT);
}

// Hierarchical grid barrier. c8 = base of 8 counter lines (128 B apart),
// pre-zeroed by hipMemsetAsync. Arrival: release fetch_add on line
// blockIdx&7 (<=13 contenders per line). Wait: wave-0 lanes 0..7 poll the
// 8 lines with relaxed loads, butterfly-sum, sleep between polls.
__device__ __forceinline__ void gbar(unsigned* c8) {
    __syncthreads();
    if (threadIdx.x == 0)
        __hip_atomic_fetch_add(&c8[(blockIdx.x & 7) * 32], 1u,
                               __ATOMIC_RELEASE, __HIP_MEMORY_SCOPE_AGENT);
    if (threadIdx.x < 64) {
        const int lane = threadIdx.x;
        unsigned t;
        do {
            __builtin_amdgcn_s_sleep(1);
            unsigned v = (lane < 8)
                ? __hip_atomic_load(&c8[lane * 32], __ATOMIC_RELAXED,
                                    __HIP_MEMORY_SCOPE_AGENT)
                : 0u;
            t = v;
            t += __shfl_xor(t, 1, 64);
            t += __shfl_xor(t, 2, 64);
            t += __shfl_xor(t, 4, 64);
            t = __shfl(t, 0, 64);
        } while (t != NBLK);
        __threadfence();
    }
    __syncthreads();
}

__device__ __forceinline__ float dot2(float2 w, float2 x) {
    return fmaf(w.x, x.x, w.y * x.y);
}
__device__ __forceinline__ float dot4(float4 w, float4 x) {
    return fmaf(w.x, x.x, fmaf(w.y, x.y, fmaf(w.z, x.z, w.w * x.w)));
}

__global__ __launch_bounds__(256) void fused_kernel(
    const float* __restrict__ x_last,  // [H]
    const float* __restrict__ W_ih,    // [3, 4H, H]
    const float* __restrict__ b_ih,    // [3, 4H]
    const float* __restrict__ b_hh,    // [3, 4H]
    const float* __restrict__ W_fc,    // [FCN, H]
    const float* __restrict__ b_fc,
    const float* __restrict__ W_l1,    // [L1N, FCN]
    const float* __restrict__ b_l1,
    const float* __restrict__ W_l2,    // [L2N, L1N]
    const float* __restrict__ b_l2,
    float* __restrict__ hb,            // ws: [3*H]
    float* __restrict__ fc_o,          // ws: [FCN]
    float* __restrict__ l1_o,          // ws: [L1N]
    unsigned* __restrict__ bars,       // ws: 5 stages x 8 lines (zeroed)
    float* __restrict__ out)           // [L2N]
{
    __shared__ __align__(16) float s_x[512];
    const int tid  = threadIdx.x;
    const int lane = tid & 63;
    const int gw   = (blockIdx.x << 2) | (tid >> 6);  // 0..399

    // ================= PREFETCH ALL WEIGHTS (no activation dependence) ====
    const float4 z4 = make_float4(0.f, 0.f, 0.f, 0.f);

    // LSTM rows (i,g,o) for h-element gw, all 3 layers
    float2 wA[3][3];
    float  bA[3][3];
    if (gw < H) {
#pragma unroll
        for (int l = 0; l < 3; ++l) {
            const float* Wl = W_ih + (size_t)l * 4 * H * H;
            wA[l][0] = ((const float2*)(Wl + (size_t)(0 * H + gw) * H))[lane];
            wA[l][1] = ((const float2*)(Wl + (size_t)(2 * H + gw) * H))[lane];
            wA[l][2] = ((const float2*)(Wl + (size_t)(3 * H + gw) * H))[lane];
            bA[l][0] = b_ih[l * 4 * H + 0 * H + gw] + b_hh[l * 4 * H + 0 * H + gw];
            bA[l][1] = b_ih[l * 4 * H + 2 * H + gw] + b_hh[l * 4 * H + 2 * H + gw];
            bA[l][2] = b_ih[l * 4 * H + 3 * H + gw] + b_hh[l * 4 * H + 3 * H + gw];
        }
    }

    // FC row gw (gw always < 400 == FCN)
    const float2 wfc = ((const float2*)(W_fc + (size_t)gw * H))[lane];
    const float  bfc = b_fc[gw];

    // L1 rows gw and gw+400 (K=400 -> 100 float4; lane covers k=lane, lane+64)
    const int k1a = lane;                       // < 100 always
    const int k1b = (lane + 64 < 100) ? lane + 64 : 99;
    float4 w1a0 = ((const float4*)(W_l1 + (size_t)gw * FCN))[k1a];
    float4 w1a1 = ((const float4*)(W_l1 + (size_t)gw * FCN))[k1b];
    if (lane + 64 >= 100) w1a1 = z4;
    const float b1a = b_l1[gw];
    const bool has2 = (gw < L1N - NWAVE);       // gw < 100
    float4 w1b0 = z4, w1b1 = z4;
    float  b1b  = 0.f;
    if (has2) {
        const float* r = W_l1 + (size_t)(gw + NWAVE) * FCN;
        w1b0 = ((const float4*)r)[k1a];
        w1b1 = ((const float4*)r)[k1b];
        if (lane + 64 >= 100) w1b1 = z4;
        b1b = b_l1[gw + NWAVE];
    }

    // L2 row gw (K=500 -> 125 float4; lane covers k=lane, lane+64)
    const int k2b = (lane + 64 < 125) ? lane + 64 : 124;
    float4 w2a = z4, w2b = z4;
    float  b2  = 0.f;
    if (gw < L2N) {
        const float* r = W_l2 + (size_t)gw * L1N;
        w2a = ((const float4*)r)[lane];
        w2b = ((const float4*)r)[k2b];
        if (lane + 64 >= 125) w2b = z4;
        b2 = b_l2[gw];
    }

    // ================= STAGES =============================================
    // 3 LSTM layers (h0=c0=0: only i,g,o gates; W_hh contributes 0)
#pragma unroll
    for (int l = 0; l < 3; ++l) {
        if (tid < H)
            s_x[tid] = (l == 0) ? x_last[tid] : cohLoad(&hb[(l - 1) * H + tid]);
        __syncthreads();
        if (gw < H) {
            const float2 xv = ((const float2*)s_x)[lane];
            float pi = wave_reduce(dot2(wA[l][0], xv));
            float pg = wave_reduce(dot2(wA[l][1], xv));
            float po = wave_reduce(dot2(wA[l][2], xv));
            if (lane == 0) {
                const float cc = sigmoidf_(pi + bA[l][0]) * tanhf(pg + bA[l][1]);
                cohStore(&hb[l * H + gw], sigmoidf_(po + bA[l][2]) * tanhf(cc));
            }
        }
        gbar(bars + l * 256);
    }

    // FC
    if (tid < H) s_x[tid] = cohLoad(&hb[2 * H + tid]);
    __syncthreads();
    {
        const float2 xv = ((const float2*)s_x)[lane];
        float p = wave_reduce(dot2(wfc, xv));
        if (lane == 0) cohStore(&fc_o[gw], p + bfc);
    }
    gbar(bars + 3 * 256);

    // L1
    for (int i = tid; i < FCN; i += 256) s_x[i] = cohLoad(&fc_o[i]);
    __syncthreads();
    {
        const float4 x0 = ((const float4*)s_x)[k1a];
        const float4 x1 = ((const float4*)s_x)[k1b];
        float acc = wave_reduce(dot4(w1a0, x0) + dot4(w1a1, x1));
        if (lane == 0) cohStore(&l1_o[gw], acc + b1a);
        if (has2) {
            float acc2 = wave_reduce(dot4(w1b0, x0) + dot4(w1b1, x1));
            if (lane == 0) cohStore(&l1_o[gw + NWAVE], acc2 + b1b);
        }
    }
    gbar(bars + 4 * 256);

    // L2 -> out
    for (int i = tid; i < L1N; i += 256) s_x[i] = cohLoad(&l1_o[i]);
    __syncthreads();
    if (gw < L2N) {
        const float4 x0 = ((const float4*)s_x)[lane];
        const float4 x1 = ((const float4*)s_x)[k2b];
        float acc = wave_reduce(dot4(w2a, x0) + dot4(w2b, x1));
        if (lane == 0) out[gw] = acc + b2;
    }
}

extern "C" void kernel_launch(void* const* d_in, const int* in_sizes, int n_in,
                              void* d_out, int out_size, void* d_ws, size_t ws_size,
                              hipStream_t stream) {
    const float* inputs = (const float*)d_in[0];
    const float* W_ih   = (const float*)d_in[1];
    // d_in[2] = W_hh (unused: h0 = 0)
    const float* b_ih   = (const float*)d_in[3];
    const float* b_hh   = (const float*)d_in[4];
    const float* W_fc   = (const float*)d_in[5];
    const float* b_fc   = (const float*)d_in[6];
    const float* W_l1   = (const float*)d_in[7];
    const float* b_l1   = (const float*)d_in[8];
    const float* W_l2   = (const float*)d_in[9];
    const float* b_l2   = (const float*)d_in[10];
    float* out = (float*)d_out;

    float* ws   = (float*)d_ws;
    float* hb   = ws + 0;     // 3*128
    float* fc_o = ws + 512;   // 400
    float* l1_o = ws + 1024;  // 500
    unsigned* bars = (unsigned*)((char*)d_ws + 16384);  // 5 stages * 256 uints

    const float* x_last = inputs + (size_t)(STEPS - 1) * H;

    hipMemsetAsync(bars, 0, 5 * 256 * sizeof(unsigned), stream);
    fused_kernel<<<NBLK, 256, 0, stream>>>(
        x_last, W_ih, b_ih, b_hh, W_fc, b_fc, W_l1, b_l1, W_l2, b_l2,
        hb, fc_o, l1_o, bars, out);
}